// Round 1
// baseline (202.620 us; speedup 1.0000x reference)
//
#include <hip/hip_runtime.h>
#include <math.h>

#define NB 16
#define NA 5
#define NH 96
#define NW 96
#define MAXT 50
#define NC 40
#define CH 45      // 5 + NUM_CLASSES
#define TGT_W 53   // 13 + NUM_CLASSES
#define NCELL (NH*NW)          // 9216
#define NTOT (NB*NA*NH*NW)     // 737280 cells
#define IGNORE_THRES 0.5f

// Conf streaming geometry:
//   total float4s = NTOT*CH/4 = 8,294,400
//   CONFB*1024 threads = 691,200 ; 8,294,400 / 691,200 = 12 exactly
//   stride 691,200 % 45 == 0  ->  (q % 45) is loop-invariant per thread
#define CONFB 675
#define THREADS_CONF (CONFB*1024)   // 691200

// anchors / SCALE
__device__ __constant__ float c_AW[5] = {1.f, 2.f, 4.f, 2.f, 4.f};
__device__ __constant__ float c_AH[5] = {1.f, 2.f, 4.f, 4.f, 2.f};

// ws layout (bytes), zeroed by hipMemsetAsync(d_ws, 0, 160):
//  @0    acc[10] doubles: [0]=conf bce (all cells, tconf=0)
//        [1]=cmf_bce corr [2]=cmf cnt corr [3]=mask_bce [4]=cls ce
//        [5..8]=x,y,w,h sq err [9]=nM
//  @80   corG[16] ints (per-batch nCorrect)  (fully written by tgt blocks)
//  @144  propI int (nProposals)

__device__ __forceinline__ float softplusf(float p) {
    return fmaxf(p, 0.f) + log1pf(expf(-fabsf(p)));
}

// ---------- Kernel 1 (fused): blocks 0..15 = target analysis + corrections,
//                              blocks 16..  = coalesced conf streaming ----------
__global__ __launch_bounds__(1024) void fused(
    const float* __restrict__ pred, const float* __restrict__ tgt,
    const int* __restrict__ tsz, double* acc, int* corG, int* propI) {

    // shared (declared once; each path uses its subset)
    __shared__ int   s_key[MAXT], s_best[MAXT], s_ign[MAXT], s_lbl[MAXT];
    __shared__ float s_fx[MAXT], s_fy[MAXT], s_gw[MAXT], s_gh[MAXT];
    __shared__ int   s_cor[MAXT];
    __shared__ int   s_sl[MAXT * NA][6];     // per-block correction slots
    __shared__ double red[16][9];
    __shared__ float sb[16];
    __shared__ int   sp[16];

    const int wave = threadIdx.x >> 6, lane = threadIdx.x & 63;

    if (blockIdx.x >= 16) {
        // ===== conf streaming: fully-coalesced float4 over the whole tensor =====
        const int cb = blockIdx.x - 16;
        const unsigned q0 = (unsigned)cb * 1024u + threadIdx.x;
        const unsigned j  = q0 % 45u;                 // loop-invariant
        const bool match  = (j == 0u) || (j == 11u) || (j == 22u) || (j == 33u);
        const int  e      = (int)(j / 11u);           // which float4 component is ch0
        const float4* __restrict__ p4 = (const float4*)pred;

        float bce = 0.f; int prop = 0;
        unsigned q = q0;
        #pragma unroll 4
        for (int it = 0; it < 12; ++it, q += (unsigned)THREADS_CONF) {
            float4 v = p4[q];
            if (match) {
                float p = (e == 0) ? v.x : ((e == 1) ? v.y : ((e == 2) ? v.z : v.w));
                bce  += softplusf(p);
                prop += (p > 0.f) ? 1 : 0;
            }
        }
        #pragma unroll
        for (int off = 32; off; off >>= 1) {
            bce  += __shfl_down(bce, off);
            prop += __shfl_down(prop, off);
        }
        if (lane == 0) { sb[wave] = bce; sp[wave] = prop; }
        __syncthreads();
        if (threadIdx.x == 0) {
            float tb = 0.f; int tp = 0;
            #pragma unroll
            for (int w2 = 0; w2 < 16; ++w2) { tb += sb[w2]; tp += sp[w2]; }
            atomicAdd(&acc[0], (double)tb);
            atomicAdd(propI, tp);
        }
        return;
    }

    // ===== target blocks: one block per batch =====
    const int b = blockIdx.x;
    const int size_b = tsz[b];

    // ---- Phase 1: wave w handles targets t = w, w+16, ... ----
    for (int t = wave; t < MAXT; t += 16) {
        const bool valid = t < size_b;
        const float* row = tgt + ((size_t)b * MAXT + t) * TGT_W;
        const float inv_s = 0.0625f;
        float gx = row[0] * inv_s, gy = row[1] * inv_s;
        float gh_ = row[3] * inv_s, gw_ = row[4] * inv_s;
        int gi = (int)gx, gj = (int)gy;

        // label argmax across lanes (first-max)
        float lv = (lane < NC) ? row[13 + lane] : -1e30f;
        int   li = (lane < NC) ? lane : (1 << 30);
        #pragma unroll
        for (int off = 32; off; off >>= 1) {
            float ov = __shfl_xor(lv, off);
            int   oi = __shfl_xor(li, off);
            if (ov > lv || (ov == lv && oi < li)) { lv = ov; li = oi; }
        }
        int lbl = li;

        // anchor IoUs (redundant per lane)
        float best_iou = -1e30f; int best = 0; int ign = 0;
        #pragma unroll
        for (int a = 0; a < 5; ++a) {
            float iw = fmaxf(fminf(gw_, c_AW[a]) + 1.f, 0.f);
            float ih = fmaxf(fminf(gh_, c_AH[a]) + 1.f, 0.f);
            float inter = iw * ih;
            float iou = inter / ((gw_ + 1.f) * (gh_ + 1.f) +
                                 (c_AW[a] + 1.f) * (c_AH[a] + 1.f) - inter + 1e-16f);
            if (iou > IGNORE_THRES) ign |= (1 << a);
            if (iou > best_iou) { best_iou = iou; best = a; }
        }

        // coalesced pred fragment at (b,best,gj,gi)
        size_t pbase = ((((size_t)b * NA + best) * NH + gj) * NW + gi) * CH;
        float pv = (lane < CH) ? pred[pbase + lane] : -1e30f;
        float pc = __shfl(pv, 0);
        float px = __shfl(pv, 1) + (float)gi;
        float py = __shfl(pv, 2) + (float)gj;
        float ph = expf(__shfl(pv, 3)) * c_AH[best];
        float pw = expf(__shfl(pv, 4)) * c_AW[best];

        float gx1 = gx - gw_ * 0.5f, gx2 = gx + gw_ * 0.5f;
        float gy1 = gy - gh_ * 0.5f, gy2 = gy + gh_ * 0.5f;
        float px1 = px - pw * 0.5f, px2 = px + pw * 0.5f;
        float py1 = py - ph * 0.5f, py2 = py + ph * 0.5f;
        float iw2 = fmaxf(fminf(gx2, px2) - fmaxf(gx1, px1) + 1.f, 0.f);
        float ih2 = fmaxf(fminf(gy2, py2) - fmaxf(gy1, py1) + 1.f, 0.f);
        float inter2 = iw2 * ih2;
        float ga = (gx2 - gx1 + 1.f) * (gy2 - gy1 + 1.f);
        float pa = (px2 - px1 + 1.f) * (py2 - py1 + 1.f);
        float iou2 = inter2 / (ga + pa - inter2 + 1e-16f);

        // pred cls argmax across lanes (first-max)
        float cv = (lane >= 5 && lane < CH) ? pv : -1e30f;
        int   ci = (lane >= 5 && lane < CH) ? (lane - 5) : (1 << 30);
        #pragma unroll
        for (int off = 32; off; off >>= 1) {
            float ov = __shfl_xor(cv, off);
            int   oi = __shfl_xor(ci, off);
            if (ov > cv || (ov == cv && oi < ci)) { cv = ov; ci = oi; }
        }
        bool correct = valid && (iou2 > 0.5f) && (ci == lbl) && (pc > 0.5f);

        if (lane == 0) {
            s_key[t] = valid ? (gj * NW + gi) : -1;
            s_best[t] = best; s_ign[t] = ign; s_lbl[t] = lbl;
            s_fx[t] = gx - (float)gi; s_fy[t] = gy - (float)gj;
            s_gw[t] = gw_; s_gh[t] = gh_;
            s_cor[t] = correct ? 1 : 0;
        }
    }
    __syncthreads();

    if (threadIdx.x == 0) {
        int c = 0;
        for (int t = 0; t < MAXT; ++t) c += s_cor[t];
        corG[b] = c;
    }

    // ---- Phase 2: one thread per target; owner = last valid with same key;
    //      owners emit per-anchor correction slots into shared ----
    {
        const int t = threadIdx.x;
        if (t < MAXT) {
            const int myKey = s_key[t];
            bool owner = (myKey >= 0);
            if (owner)
                for (int u = t + 1; u < MAXT; ++u)
                    if (s_key[u] == myKey) { owner = false; break; }

            if (!owner) {
                #pragma unroll
                for (int a = 0; a < 5; ++a) s_sl[t * 5 + a][0] = 0;
            } else {
                int cm = 0x1F, m = 0;
                int w_[5] = {-1, -1, -1, -1, -1};
                for (int u = 0; u < MAXT; ++u) {
                    if (s_key[u] != myKey) continue;
                    cm &= ~s_ign[u];
                    int bn = s_best[u];
                    cm |= (1 << bn); m |= (1 << bn);
                    w_[bn] = u;
                }
                #pragma unroll
                for (int a = 0; a < 5; ++a) {
                    int* eSl = s_sl[t * 5 + a];
                    int ca = (b * NA + a) * NCELL + myKey;    // < 2^20
                    int ma = (m >> a) & 1, cma = (cm >> a) & 1;
                    eSl[0] = ca | (ma << 20) | (cma << 21) | (1 << 22);
                    if (ma) {
                        int u = w_[a];
                        eSl[1] = s_lbl[u];
                        eSl[2] = __float_as_int(s_fx[u]);
                        eSl[3] = __float_as_int(s_fy[u]);
                        eSl[4] = __float_as_int(logf(s_gw[u] / c_AW[a] + 1e-16f));
                        eSl[5] = __float_as_int(logf(s_gh[u] / c_AH[a] + 1e-16f));
                    }
                }
            }
        }
    }
    __syncthreads();

    // ---- Phase 3: corrections; wave w processes slots s = w, w+16, ... ----
    double loc[9];
    #pragma unroll
    for (int c = 0; c < 9; ++c) loc[c] = 0.0;

    for (int s = wave; s < MAXT * NA; s += 16) {
        int flags = s_sl[s][0];
        if (!(flags & (1 << 22))) continue;
        int ca = flags & 0xFFFFF;
        int ma = (flags >> 20) & 1, cma = (flags >> 21) & 1;
        size_t base = (size_t)ca * CH;
        float v = (lane < CH) ? pred[base + lane] : -1e30f;
        float p = __shfl(v, 0);
        float s0 = softplusf(p);
        int cmf = (cma != ma) ? 1 : 0;
        loc[0] += (cmf ? (double)(s0 - p * (float)ma) : 0.0) - (double)s0;
        loc[1] += (double)(cmf - 1);
        if (ma) {
            loc[2] += (double)(s0 - p);
            loc[8] += 1.0;
            float x = __shfl(v, 1), y = __shfl(v, 2);
            float hh = __shfl(v, 3), wv = __shfl(v, 4);
            float fx = __int_as_float(s_sl[s][2]), fy = __int_as_float(s_sl[s][3]);
            float tw_ = __int_as_float(s_sl[s][4]), th_ = __int_as_float(s_sl[s][5]);
            int lbl = s_sl[s][1];
            loc[4] += (double)((x - fx) * (x - fx));
            loc[5] += (double)((y - fy) * (y - fy));
            loc[6] += (double)((wv - tw_) * (wv - tw_));
            loc[7] += (double)((hh - th_) * (hh - th_));
            float cvv = (lane >= 5 && lane < CH) ? v : -1e30f;
            float mx = cvv;
            #pragma unroll
            for (int off = 32; off; off >>= 1) mx = fmaxf(mx, __shfl_xor(mx, off));
            float ex = (lane >= 5 && lane < CH) ? expf(v - mx) : 0.f;
            #pragma unroll
            for (int off = 32; off; off >>= 1) ex += __shfl_xor(ex, off);
            float cll = __shfl(v, 5 + lbl);
            loc[3] += (double)(logf(ex) + mx - cll);
        }
    }

    if (lane == 0) {
        #pragma unroll
        for (int c = 0; c < 9; ++c) red[wave][c] = loc[c];
    }
    __syncthreads();
    if (threadIdx.x < 9) {
        double sum = 0.0;
        #pragma unroll
        for (int w2 = 0; w2 < 16; ++w2) sum += red[w2][threadIdx.x];
        if (sum != 0.0) atomicAdd(&acc[1 + threadIdx.x], sum);
    }
}

// ---------- Kernel 2: finalize (scalar) ----------
__global__ __launch_bounds__(64) void finalize(
    const double* __restrict__ acc, const int* __restrict__ corG,
    const int* __restrict__ tsz, const int* __restrict__ propI, float* out) {
    if (threadIdx.x != 0) return;
    int nCor = 0, nGT = 0;
    for (int b = 0; b < NB; ++b) { nCor += corG[b]; nGT += tsz[b]; }
    int nProp = *propI;

    double nM = acc[9];
    double inv_nM = 1.0 / (nM > 0.0 ? nM : 1e-16);
    double l_coord = (acc[5] + acc[6] + acc[7] + acc[8]) * inv_nM;
    double sum_cmf = (double)NTOT + acc[2];
    double l_conf = (acc[0] + acc[1]) / sum_cmf + acc[3] * inv_nM;
    double l_cls = (1.0 / (double)NB) * acc[4] * inv_nM;
    double loss = l_coord + l_conf + l_cls;
    float recall = (float)nCor / (float)(nGT > 1 ? nGT : 1);
    float precision = (nProp > 0) ? ((float)nCor / fmaxf((float)nProp, 1.f)) : 1.f;
    out[0] = (float)loss;
    out[1] = (float)l_coord;
    out[2] = (float)l_conf;
    out[3] = (float)l_cls;
    out[4] = recall;
    out[5] = precision;
}

extern "C" void kernel_launch(void* const* d_in, const int* in_sizes, int n_in,
                              void* d_out, int out_size, void* d_ws, size_t ws_size,
                              hipStream_t stream) {
    const float* pred = (const float*)d_in[0];
    const float* tgt  = (const float*)d_in[1];
    const int*   tsz  = (const int*)d_in[2];
    float* out = (float*)d_out;

    double* acc = (double*)d_ws;
    int* corG   = (int*)((char*)d_ws + 80);
    int* propI  = (int*)((char*)d_ws + 144);

    hipMemsetAsync(d_ws, 0, 160, stream);
    fused<<<16 + CONFB, 1024, 0, stream>>>(pred, tgt, tsz, acc, corG, propI);
    finalize<<<1, 64, 0, stream>>>(acc, corG, tsz, propI, out);
}